// Round 3
// baseline (388.783 us; speedup 1.0000x reference)
//
#include <hip/hip_runtime.h>
#include <hip/hip_bf16.h>
#include <hip/hip_cooperative_groups.h>

namespace cg = cooperative_groups;

// Problem: B=8, T=2048, C=1024, HS=64. fp32 in/out.
// d_in: x[8,2048,1024], Wq[1024,64], Wk[1024,64], Wv[1024,64]
// d_out: [8,2048,64] fp32
// Workspace: q bf16 [16384][64] (pre-scaled log2e/32), k bf16 [16384][64],
//            vT bf16 [8][64][2048] (s-permuted within 64-blocks),
//            Wt bf16 [192][1024]  (~6.4 MB)
// Single cooperative kernel, 3 phases separated by grid.sync():
//   W-transpose -> QKV projection -> causal flash attention.

#define T_SEQ 2048
#define C_DIM 1024
#define HS 64
#define BT 16384

typedef short s8v __attribute__((ext_vector_type(8)));   // 8 bf16
typedef float f4v __attribute__((ext_vector_type(4)));   // MFMA C/D

__device__ inline unsigned short f2bf(float f) {
  union { float f; unsigned u; } a; a.f = f;
  unsigned r = a.u + 0x7fffu + ((a.u >> 16) & 1u);  // RNE
  return (unsigned short)(r >> 16);
}

// HW-packed f32x2 -> bf16x2 (v_cvt_pk_bf16_f32)
__device__ inline unsigned pk2(float a, float b) {
  union { __hip_bfloat162 h; unsigned u; } c;
  c.h = __float22bfloat162_rn(make_float2(a, b));
  return c.u;
}

__device__ inline s8v cvt8(float4 v0, float4 v1) {
  union { unsigned u[4]; s8v v; } r;
  r.u[0] = pk2(v0.x, v0.y); r.u[1] = pk2(v0.z, v0.w);
  r.u[2] = pk2(v1.x, v1.y); r.u[3] = pk2(v1.z, v1.w);
  return r.v;
}

// async global->LDS, 16 B/lane. LDS base MUST be wave-uniform (SGPR):
// HW writes base + lane*16.
__device__ inline void gl_lds16(const void* g, unsigned char* lds_base,
                                unsigned uniform_byte_off) {
  __builtin_amdgcn_global_load_lds(
      (const __attribute__((address_space(1))) unsigned int*)g,
      (__attribute__((address_space(3))) unsigned int*)(lds_base + uniform_byte_off),
      16, 0, 0);
}

// ---------------- shared memory: one union across all phases -------------
// qk:     80 KB  (QKV staging, double-buffered)
// at.p:   72 KB  (per-wave P tiles, attn main loop)
// mg.mo:  64 KB  (per-wave O partials, attn merge)
// wtile:  16.3KB (W transpose staging)
union __align__(16) FusedSh {
  struct { unsigned char a[2][16384]; unsigned char b[2][24576]; } qk;
  struct { unsigned short p[8][4][16 * 72]; } at;
  struct { float mo[8][32][64]; } mg;
  float wtile[64][65];
};

__global__ __launch_bounds__(512, 2) void fused_kernel(
    const float* __restrict__ x, const float* __restrict__ Wq,
    const float* __restrict__ Wk, const float* __restrict__ Wv,
    unsigned short* __restrict__ wt, unsigned short* __restrict__ qws,
    unsigned short* __restrict__ kws, unsigned short* __restrict__ vtws,
    float* __restrict__ out) {
  __shared__ FusedSh sh;
  __shared__ float ml[8][32];

  cg::grid_group grid = cg::this_grid();

  const int tid  = threadIdx.x;
  const int bid  = blockIdx.x;
  const int wv   = tid >> 6;
  const int lane = tid & 63;
  const int m    = lane & 15;
  const int quad = lane >> 4;

  // ---------------- Phase 1: W transpose (blocks 0..47) ------------------
  if (bid < 48) {
    const int mat = bid >> 4, kt = bid & 15;
    const float* W = (mat == 0) ? Wq : ((mat == 1) ? Wk : Wv);
    const int n = tid & 63, kr = tid >> 6;          // kr 0..7
#pragma unroll
    for (int j = 0; j < 8; ++j) {
      const int kl = j * 8 + kr;
      sh.wtile[kl][n] = W[(kt * 64 + kl) * HS + n];
    }
    __syncthreads();
    const int n2 = tid >> 3, kp = tid & 7;
    unsigned int* orow =
        (unsigned int*)(wt + (size_t)(mat * 64 + n2) * C_DIM + kt * 64);
#pragma unroll
    for (int i = 0; i < 4; ++i) {
      const int k0 = kp * 8 + i * 2;
      unsigned lo = f2bf(sh.wtile[k0][n2]);
      unsigned hi = f2bf(sh.wtile[k0 + 1][n2]);
      orow[kp * 4 + i] = lo | (hi << 16);
    }
  }
  __threadfence();
  grid.sync();
  __threadfence();

  // ---------------- Phase 2: QKV projection ------------------------------
  // 256 blocks x 512 threads; 64 rows/block (waves 0-3: rows +0..31,
  // waves 4-7: rows +32..63), shared B (wt) staging buffer. BK = 64,
  // 16 double-buffered iterations, glds 16B with XOR'd 16B parts.
  {
    const int wq = wv & 3, th = wv >> 2;
    const int mh = wq >> 1, ng = (wq & 1) * 6;
    const int row0 = bid * 64;

    f4v acc[6];
#pragma unroll
    for (int j = 0; j < 6; ++j) acc[j] = (f4v)0.0f;

    // wave-uniform LDS slot base (bytes); HW adds lane*16
    const unsigned au = (unsigned)__builtin_amdgcn_readfirstlane(tid & 448) << 4;

    // A: 1024 slots (64 rows x 16 parts), 2/thread. slot s -> row s>>4,
    // part (s&15)^(row&15). B: 1536 slots (192 rows x 8 parts), 3/thread.
    const float* agp[2];
#pragma unroll
    for (int j = 0; j < 2; ++j) {
      const int s = tid + j * 512;
      const int r = s >> 4, p = (s & 15) ^ (r & 15);
      agp[j] = x + (size_t)(row0 + r) * C_DIM + p * 4;
    }
    const unsigned short* bgp[3];
#pragma unroll
    for (int j = 0; j < 3; ++j) {
      const int s = tid + j * 512;
      const int n = s >> 3, p = (s & 7) ^ (n & 7);
      bgp[j] = wt + (size_t)n * C_DIM + p * 8;
    }

    // fragment LDS byte offsets. A row r' = th*32+mh*16+m (r'&15 == m)
    int aoff[2][2];
#pragma unroll
    for (int c = 0; c < 2; ++c)
#pragma unroll
      for (int t = 0; t < 2; ++t)
        aoff[c][t] =
            (((th * 32 + mh * 16 + m) * 16) + ((c * 8 + 2 * quad + t) ^ m)) << 4;
    int boff[6][2];
#pragma unroll
    for (int j = 0; j < 6; ++j) {
      const int n = (ng + j) * 16 + m;
#pragma unroll
      for (int c = 0; c < 2; ++c)
        boff[j][c] = (n * 8 + ((c * 4 + quad) ^ (n & 7))) << 4;
    }

#define STAGE(buf, kk)                                                       \
  do {                                                                       \
    _Pragma("unroll") for (int j = 0; j < 2; ++j)                            \
        gl_lds16(agp[j] + (kk), sh.qk.a[buf], au + (unsigned)(j * 8192));    \
    _Pragma("unroll") for (int j = 0; j < 3; ++j)                            \
        gl_lds16(bgp[j] + (kk), sh.qk.b[buf], au + (unsigned)(j * 8192));    \
  } while (0)

    STAGE(0, 0);
    for (int it = 0; it < 16; ++it) {
      __syncthreads();                   // stage(it) landed (vmcnt drain)
      if (it < 15) STAGE((it + 1) & 1, (it + 1) * 64);
      const unsigned char* aB = sh.qk.a[it & 1];
      const unsigned char* bB = sh.qk.b[it & 1];
#pragma unroll
      for (int c = 0; c < 2; ++c) {
        float4 xa = *(const float4*)(aB + aoff[c][0]);
        float4 xb = *(const float4*)(aB + aoff[c][1]);
        s8v a = cvt8(xa, xb);
#pragma unroll
        for (int j = 0; j < 6; ++j) {
          s8v b = *(const s8v*)(bB + boff[j][c]);
          acc[j] = __builtin_amdgcn_mfma_f32_16x16x32_bf16(a, b, acc[j], 0, 0, 0);
        }
      }
    }
#undef STAGE

    const float qscale = 1.4426950408889634f / 32.0f;  // log2e / sqrt(C)
#pragma unroll
    for (int j = 0; j < 6; ++j) {
      const int nt = ng + j;
      const int mat = nt >> 2, ct = nt & 3;
      const int col = ct * 16 + m;
#pragma unroll
      for (int r = 0; r < 4; ++r) {
        const int row = row0 + th * 32 + mh * 16 + quad * 4 + r;
        const float v = acc[j][r];
        if (mat == 0) {
          qws[row * HS + col] = f2bf(v * qscale);
        } else if (mat == 1) {
          kws[row * HS + col] = f2bf(v);
        } else {
          const int bb = row >> 11, t = row & 2047;
          // s-permuted V^T slot within each 64-block (matches packed P)
          const int tp = (t & ~63) | (((t & 15) << 2) | ((t >> 4) & 3));
          vtws[(bb * HS + col) * T_SEQ + tp] = f2bf(v);
        }
      }
    }
  }
  __threadfence();
  grid.sync();
  __threadfence();

  // ---------------- Phase 3: causal flash attention ----------------------
  // 64 q-rows/block. XCD pinning: batch = bid & 7 (its K/V L2-resident).
  // Block pr = bid>>3 handles COMPLEMENTARY q-groups pr and 63-pr:
  // nstS + nstB == 33 for every pr -> perfect static balance at 1 blk/CU.
  // Each wave holds 4 q-tiles; low-range s-tiles share one K/V fragment
  // load across all 4 (64 MFMA / 16 KB). P stored j-permuted
  // (j = 4*(s&15) + (s>>4)): 2 cvt_pk + one 8B LDS write per row; V^T was
  // stored with the same permutation in phase 2.
  {
    const int b  = bid & 7;
    const int pr = bid >> 3;
    const int rS = pr * 32;
    const int rB = (63 - pr) * 32;
    const int grS = b * T_SEQ + rS;
    const int grB = b * T_SEQ + rB;

    const unsigned short* qpS = qws + (size_t)(grS + m) * HS + quad * 8;
    const unsigned short* qpB = qws + (size_t)(grB + m) * HS + quad * 8;
    s8v aq[4][2];
    aq[0][0] = *(const s8v*)qpS;
    aq[0][1] = *(const s8v*)(qpS + 32);
    aq[1][0] = *(const s8v*)(qpS + 16 * HS);
    aq[1][1] = *(const s8v*)(qpS + 16 * HS + 32);
    aq[2][0] = *(const s8v*)qpB;
    aq[2][1] = *(const s8v*)(qpB + 32);
    aq[3][0] = *(const s8v*)(qpB + 16 * HS);
    aq[3][1] = *(const s8v*)(qpB + 16 * HS + 32);

    float li[4][4];
    f4v o[4][4];
#pragma unroll
    for (int t = 0; t < 4; ++t)
#pragma unroll
      for (int i = 0; i < 4; ++i) { li[t][i] = 0.f; o[t][i] = (f4v)0.0f; }

    const int nstS = (rS + 32 + 63) >> 6;
    const int nstB = (rB + 32 + 63) >> 6;
    const int qb0 = rS + quad * 4;
    const int qb1 = qb0 + 16;
    const int qb2 = rB + quad * 4;
    const int qb3 = qb2 + 16;
    const unsigned short* kbase = kws + (size_t)b * T_SEQ * HS;
    const unsigned short* vbase = vtws + (size_t)b * HS * T_SEQ;

#define QKT(t, qbase)                                                        \
  {                                                                          \
    f4v s_[4];                                                               \
    _Pragma("unroll") for (int ns = 0; ns < 4; ++ns) {                       \
      f4v u_ = (f4v)0.0f;                                                    \
      u_ = __builtin_amdgcn_mfma_f32_16x16x32_bf16(aq[t][0], kf[ns][0], u_, 0, 0, 0); \
      u_ = __builtin_amdgcn_mfma_f32_16x16x32_bf16(aq[t][1], kf[ns][1], u_, 0, 0, 0); \
      s_[ns] = u_;                                                           \
    }                                                                        \
    _Pragma("unroll") for (int r = 0; r < 4; ++r) {                          \
      const int qr = (qbase) + r;                                            \
      const float p0 = (sm      > qr) ? 0.f : __builtin_amdgcn_exp2f(s_[0][r]); \
      const float p1 = (sm + 16 > qr) ? 0.f : __builtin_amdgcn_exp2f(s_[1][r]); \
      const float p2 = (sm + 32 > qr) ? 0.f : __builtin_amdgcn_exp2f(s_[2][r]); \
      const float p3 = (sm + 48 > qr) ? 0.f : __builtin_amdgcn_exp2f(s_[3][r]); \
      li[t][r] += (p0 + p1) + (p2 + p3);                                     \
      *(uint2*)&sh.at.p[wv][t][(quad * 4 + r) * 72 + m * 4] =                \
          make_uint2(pk2(p0, p1), pk2(p2, p3));                              \
    }                                                                        \
  }

#define PVT(t)                                                               \
  {                                                                          \
    const unsigned short* pl_ = sh.at.p[wv][t];                              \
    s8v a0_ = *(const s8v*)&pl_[m * 72 + quad * 8];                          \
    s8v a1_ = *(const s8v*)&pl_[m * 72 + 32 + quad * 8];                     \
    _Pragma("unroll") for (int hn = 0; hn < 4; ++hn) {                       \
      o[t][hn] = __builtin_amdgcn_mfma_f32_16x16x32_bf16(a0_, vf[hn][0], o[t][hn], 0, 0, 0); \
      o[t][hn] = __builtin_amdgcn_mfma_f32_16x16x32_bf16(a1_, vf[hn][1], o[t][hn], 0, 0, 0); \
    }                                                                        \
  }

    for (int st = wv; st < nstB; st += 8) {
      const int s0 = st * 64;

      s8v kf[4][2];
#pragma unroll
      for (int ns = 0; ns < 4; ++ns) {
        const unsigned short* kp = &kbase[(size_t)(s0 + ns * 16 + m) * HS + quad * 8];
        kf[ns][0] = *(const s8v*)kp;
        kf[ns][1] = *(const s8v*)(kp + 32);
      }
      s8v vf[4][2];
#pragma unroll
      for (int hn = 0; hn < 4; ++hn) {
        const unsigned short* vp = &vbase[(size_t)(hn * 16 + m) * T_SEQ + s0 + quad * 8];
        vf[hn][0] = *(const s8v*)vp;
        vf[hn][1] = *(const s8v*)(vp + 32);
      }

      const int sm = s0 + m;
      const bool low = (st < nstS);   // wave-uniform branch
      if (low) { QKT(0, qb0); QKT(1, qb1); }
      QKT(2, qb2);
      QKT(3, qb3);
      if (low) { PVT(0); PVT(1); }
      PVT(2);
      PVT(3);
    }
#undef QKT
#undef PVT

#pragma unroll
    for (int t = 0; t < 4; ++t)
#pragma unroll
      for (int r = 0; r < 4; ++r) {
        float s = li[t][r];
        s += __shfl_xor(s, 1); s += __shfl_xor(s, 2);
        s += __shfl_xor(s, 4); s += __shfl_xor(s, 8);
        li[t][r] = s;
      }

    // merge: tiles 0,1 -> rows rS..; tiles 2,3 -> rows rB..
    const int row = tid >> 4, c4 = (tid & 15) * 4;
#pragma unroll
    for (int ps = 0; ps < 2; ++ps) {
      __syncthreads();   // P region / previous pass reads complete
#pragma unroll
      for (int hn = 0; hn < 4; ++hn)
#pragma unroll
        for (int r = 0; r < 4; ++r) {
          sh.mg.mo[wv][quad * 4 + r][hn * 16 + m]      = o[2 * ps][hn][r];
          sh.mg.mo[wv][16 + quad * 4 + r][hn * 16 + m] = o[2 * ps + 1][hn][r];
        }
      if (m == 0) {
#pragma unroll
        for (int r = 0; r < 4; ++r) {
          ml[wv][quad * 4 + r]      = li[2 * ps][r];
          ml[wv][16 + quad * 4 + r] = li[2 * ps + 1][r];
        }
      }
      __syncthreads();

      float ls = 0.f;
#pragma unroll
      for (int w = 0; w < 8; ++w) ls += ml[w][row];
      const float inv = 1.0f / ls;
      float ax = 0.f, ay = 0.f, az = 0.f, aw = 0.f;
#pragma unroll
      for (int w = 0; w < 8; ++w) {
        float4 v = *(const float4*)&sh.mg.mo[w][row][c4];
        ax += v.x; ay += v.y; az += v.z; aw += v.w;
      }
      const int gr = ps ? grB : grS;
      float4 res;
      res.x = ax * inv; res.y = ay * inv; res.z = az * inv; res.w = aw * inv;
      *(float4*)&out[(size_t)(gr + row) * HS + c4] = res;
    }
  }
}

extern "C" void kernel_launch(void* const* d_in, const int* in_sizes, int n_in,
                              void* d_out, int out_size, void* d_ws, size_t ws_size,
                              hipStream_t stream) {
  const float* x  = (const float*)d_in[0];
  const float* Wq = (const float*)d_in[1];
  const float* Wk = (const float*)d_in[2];
  const float* Wv = (const float*)d_in[3];
  float* out = (float*)d_out;

  unsigned short* qws  = (unsigned short*)d_ws;          // 2 MB
  unsigned short* kws  = qws + (size_t)BT * HS;          // 2 MB
  unsigned short* vtws = kws + (size_t)BT * HS;          // 2 MB
  unsigned short* wt   = vtws + (size_t)BT * HS;         // 384 KB

  void* args[] = {(void*)&x, (void*)&Wq, (void*)&Wk, (void*)&Wv,
                  (void*)&wt, (void*)&qws, (void*)&kws, (void*)&vtws,
                  (void*)&out};
  hipLaunchCooperativeKernel((void*)fused_kernel, dim3(256), dim3(512),
                             args, 0, stream);
}

// Round 4
// 133.293 us; speedup vs baseline: 2.9168x; 2.9168x over previous
//
#include <hip/hip_runtime.h>
#include <hip/hip_bf16.h>

// Problem: B=8, T=2048, C=1024, HS=64. fp32 in/out.
// d_in: x[8,2048,1024], Wq[1024,64], Wk[1024,64], Wv[1024,64]
// d_out: [8,2048,64] fp32
// Workspace: q bf16 [16384][64] (pre-scaled log2e/32), k bf16 [16384][64],
//            vT bf16 [8][64][2048] (s-permuted within 64-blocks, see below),
//            Wt bf16 [192][1024]  (~6.4 MB)

#define T_SEQ 2048
#define C_DIM 1024
#define HS 64
#define BT 16384

typedef short s8v __attribute__((ext_vector_type(8)));   // 8 bf16
typedef float f4v __attribute__((ext_vector_type(4)));   // MFMA C/D

__device__ inline unsigned short f2bf(float f) {
  union { float f; unsigned u; } a; a.f = f;
  unsigned r = a.u + 0x7fffu + ((a.u >> 16) & 1u);  // RNE
  return (unsigned short)(r >> 16);
}

// HW-packed f32x2 -> bf16x2 (v_cvt_pk_bf16_f32)
__device__ inline unsigned pk2(float a, float b) {
  union { __hip_bfloat162 h; unsigned u; } c;
  c.h = __float22bfloat162_rn(make_float2(a, b));
  return c.u;
}

__device__ inline s8v cvt8(float4 v0, float4 v1) {
  union { unsigned u[4]; s8v v; } r;
  r.u[0] = pk2(v0.x, v0.y); r.u[1] = pk2(v0.z, v0.w);
  r.u[2] = pk2(v1.x, v1.y); r.u[3] = pk2(v1.z, v1.w);
  return r.v;
}

// async global->LDS, 16 B/lane. LDS base MUST be wave-uniform (SGPR):
// HW writes base + lane*16.
__device__ inline void gl_lds16(const void* g, unsigned char* lds_base,
                                unsigned uniform_byte_off) {
  __builtin_amdgcn_global_load_lds(
      (const __attribute__((address_space(1))) unsigned int*)g,
      (__attribute__((address_space(3))) unsigned int*)(lds_base + uniform_byte_off),
      16, 0, 0);
}

// ------------- Kernel 0: W transpose via LDS (coalesced both ways) -------
__global__ __launch_bounds__(256) void wt_kernel(
    const float* __restrict__ Wq, const float* __restrict__ Wk,
    const float* __restrict__ Wv, unsigned short* __restrict__ wt) {
  __shared__ float tile[64][65];
  const int bid = blockIdx.x;
  const int mat = bid >> 4, kt = bid & 15;
  const float* W = (mat == 0) ? Wq : ((mat == 1) ? Wk : Wv);
  const int t = threadIdx.x;
  const int n = t & 63, kr = t >> 6;
#pragma unroll
  for (int j = 0; j < 16; ++j) {
    const int kl = j * 4 + kr;
    tile[kl][n] = W[(kt * 64 + kl) * HS + n];
  }
  __syncthreads();
  const int n2 = t >> 2, kp = t & 3;
  unsigned int* orow =
      (unsigned int*)(wt + (size_t)(mat * 64 + n2) * C_DIM + kt * 64);
#pragma unroll
  for (int i = 0; i < 8; ++i) {
    const int k0 = kp * 16 + i * 2;
    unsigned int lo = f2bf(tile[k0][n2]);
    unsigned int hi = f2bf(tile[k0 + 1][n2]);
    orow[kp * 8 + i] = lo | (hi << 16);
  }
}

// ------------- Kernel A: QKV projection, async LDS double-buffer ---------
// 256 blocks x 512 threads; 64 rows/block (waves 0-3: rows +0..31, waves
// 4-7: rows +32..63) SHARING one B (wt) staging buffer -> wt L2 re-reads
// halved vs 32-row blocks. BK = 64, 16 double-buffered iterations, glds
// 16B with XOR'd 16B parts (2-way LDS read conflict = free).
// V^T store is s-permuted within each 64-block:
//   j(s) = (s&32) | ((s&12)<<1) | ((s&16)>>2) | (s&3)
// chosen so the attn kernel's register-resident P (from swapped QK^T)
// lands exactly in PV A-fragment slot order. Contraction is unchanged
// (same bijection applied to P's s-axis and V's s-axis).
__global__ __launch_bounds__(512) void qkv_kernel(
    const float* __restrict__ x, const unsigned short* __restrict__ wt,
    unsigned short* __restrict__ qws, unsigned short* __restrict__ kws,
    unsigned short* __restrict__ vtws) {
  __shared__ unsigned char abuf[2][16384];   // 64 rows x 64 fp32 (16 parts)
  __shared__ unsigned char bbuf[2][24576];   // 192 rows x 64 bf16 (8 parts)

  const int tid  = threadIdx.x;
  const int wv   = tid >> 6;
  const int lane = tid & 63;
  const int m    = lane & 15;
  const int quad = lane >> 4;
  const int wq = wv & 3, th = wv >> 2;
  const int mh = wq >> 1, ng = (wq & 1) * 6;
  const int row0 = blockIdx.x * 64;

  f4v acc[6];
#pragma unroll
  for (int j = 0; j < 6; ++j) acc[j] = (f4v)0.0f;

  // wave-uniform LDS slot base (bytes); HW adds lane*16
  const unsigned au = (unsigned)__builtin_amdgcn_readfirstlane(tid & 448) << 4;

  // A: 1024 slots (64 rows x 16 parts), 2/thread. slot s -> row s>>4,
  // part (s&15)^(row&15). B: 1536 slots (192 rows x 8 parts), 3/thread.
  const float* agp[2];
#pragma unroll
  for (int j = 0; j < 2; ++j) {
    const int s = tid + j * 512;
    const int r = s >> 4, p = (s & 15) ^ (r & 15);
    agp[j] = x + (size_t)(row0 + r) * C_DIM + p * 4;
  }
  const unsigned short* bgp[3];
#pragma unroll
  for (int j = 0; j < 3; ++j) {
    const int s = tid + j * 512;
    const int n = s >> 3, p = (s & 7) ^ (n & 7);
    bgp[j] = wt + (size_t)n * C_DIM + p * 8;
  }

  // fragment LDS byte offsets. A row r' = th*32+mh*16+m (r'&15 == m)
  int aoff[2][2];
#pragma unroll
  for (int c = 0; c < 2; ++c)
#pragma unroll
    for (int t = 0; t < 2; ++t)
      aoff[c][t] =
          (((th * 32 + mh * 16 + m) * 16) + ((c * 8 + 2 * quad + t) ^ m)) << 4;
  int boff[6][2];
#pragma unroll
  for (int j = 0; j < 6; ++j) {
    const int n = (ng + j) * 16 + m;
#pragma unroll
    for (int c = 0; c < 2; ++c)
      boff[j][c] = (n * 8 + ((c * 4 + quad) ^ (n & 7))) << 4;
  }

#define STAGE(buf, kk)                                                       \
  do {                                                                       \
    _Pragma("unroll") for (int j = 0; j < 2; ++j)                            \
        gl_lds16(agp[j] + (kk), abuf[buf], au + (unsigned)(j * 8192));       \
    _Pragma("unroll") for (int j = 0; j < 3; ++j)                            \
        gl_lds16(bgp[j] + (kk), bbuf[buf], au + (unsigned)(j * 8192));       \
  } while (0)

  STAGE(0, 0);
  for (int it = 0; it < 16; ++it) {
    __syncthreads();                     // stage(it) landed (vmcnt drain)
    if (it < 15) STAGE((it + 1) & 1, (it + 1) * 64);
    const unsigned char* aB = abuf[it & 1];
    const unsigned char* bB = bbuf[it & 1];
#pragma unroll
    for (int c = 0; c < 2; ++c) {
      float4 xa = *(const float4*)(aB + aoff[c][0]);
      float4 xb = *(const float4*)(aB + aoff[c][1]);
      s8v a = cvt8(xa, xb);
#pragma unroll
      for (int j = 0; j < 6; ++j) {
        s8v b = *(const s8v*)(bB + boff[j][c]);
        acc[j] = __builtin_amdgcn_mfma_f32_16x16x32_bf16(a, b, acc[j], 0, 0, 0);
      }
    }
  }
#undef STAGE

  const float qscale = 1.4426950408889634f / 32.0f;  // log2e / sqrt(C)
#pragma unroll
  for (int j = 0; j < 6; ++j) {
    const int nt = ng + j;
    const int mat = nt >> 2, ct = nt & 3;
    const int col = ct * 16 + m;
#pragma unroll
    for (int r = 0; r < 4; ++r) {
      const int row = row0 + th * 32 + mh * 16 + quad * 4 + r;
      const float v = acc[j][r];
      if (mat == 0) {
        qws[row * HS + col] = f2bf(v * qscale);
      } else if (mat == 1) {
        kws[row * HS + col] = f2bf(v);
      } else {
        const int bb = row >> 11, t = row & 2047;
        const int s = t & 63;
        const int jp = (s & 32) | ((s & 12) << 1) | ((s & 16) >> 2) | (s & 3);
        vtws[(bb * HS + col) * T_SEQ + ((t & ~63) | jp)] = f2bf(v);
      }
    }
  }
}

// ------------- Kernel B: causal flash attention, 64 q-rows/block ---------
// grid 256 x 512 threads. XCD pinning: batch = blockIdx.x & 7 (its K/V =
// 512 KB stays L2-resident). Block pr = blockIdx.x>>3 handles
// COMPLEMENTARY q-groups pr and 63-pr: nstS + nstB == 33 for every pr ->
// perfect static balance at 1 block/CU. Each wave holds 4 q-tiles; low
// s-tiles share one K/V fragment load across all 4 (64 MFMA / 16 KB).
// SWAPPED QK^T: mfma(K, Q) gives C[s][q] with q = lane (m), so each lane
// owns a full P row slice -> P goes straight to PV A-frags via cvt_pk in
// REGISTERS. No P LDS buffer, no DS ops in the main loop, no DS RAW
// stall. The s-permutation j(s) (see qkv) makes lane (m,quad)'s 16 exp2
// results exactly fill its A-frag slots {8q..8q+7} u {32+8q..+7}.
__global__ __launch_bounds__(512) void attn_kernel(
    const unsigned short* __restrict__ qws, const unsigned short* __restrict__ kws,
    const unsigned short* __restrict__ vtws, float* __restrict__ out) {
  __shared__ float mo[8][32][64];   // per-wave O partials (merge phase)
  __shared__ float ml[8][32];

  const int tid  = threadIdx.x;
  const int wv   = tid >> 6;
  const int lane = tid & 63;
  const int m    = lane & 15;
  const int quad = lane >> 4;
  const int b    = blockIdx.x & 7;          // XCD-pinned batch
  const int pr   = blockIdx.x >> 3;         // 0..31 complementary pair id
  const int rS   = pr * 32;
  const int rB   = (63 - pr) * 32;
  const int grS  = b * T_SEQ + rS;
  const int grB  = b * T_SEQ + rB;

  const unsigned short* qpS = qws + (size_t)(grS + m) * HS + quad * 8;
  const unsigned short* qpB = qws + (size_t)(grB + m) * HS + quad * 8;
  s8v aq[4][2];
  aq[0][0] = *(const s8v*)qpS;
  aq[0][1] = *(const s8v*)(qpS + 32);
  aq[1][0] = *(const s8v*)(qpS + 16 * HS);
  aq[1][1] = *(const s8v*)(qpS + 16 * HS + 32);
  aq[2][0] = *(const s8v*)qpB;
  aq[2][1] = *(const s8v*)(qpB + 32);
  aq[3][0] = *(const s8v*)(qpB + 16 * HS);
  aq[3][1] = *(const s8v*)(qpB + 16 * HS + 32);

  float li[4] = {0.f, 0.f, 0.f, 0.f};
  f4v o[4][4];
#pragma unroll
  for (int t = 0; t < 4; ++t)
#pragma unroll
    for (int i = 0; i < 4; ++i) o[t][i] = (f4v)0.0f;

  const int nstS = (rS + 32 + 63) >> 6;
  const int nstB = (rB + 32 + 63) >> 6;
  const int qb0 = rS;          // lane's q-row = qb_t + m
  const int qb1 = rS + 16;
  const int qb2 = rB;
  const int qb3 = rB + 16;
  const unsigned short* kbase = kws + (size_t)b * T_SEQ * HS;
  const unsigned short* vbase = vtws + (size_t)b * HS * T_SEQ;

// Swapped QK^T + mask + exp2 + in-register P pack + PV, q-tile t (literal!)
// Lane (m,quad) holds P[s = s0+16ns+4quad+r][q = qb+m]; permuted slot
// j = 32*(ns>>1) + 8*quad + 4*(ns&1) + r -> paA covers ns{0,1} (k 0..31),
// paB covers ns{2,3} (k 32..63), matching V^T's permuted storage.
#define TILE(t, qb)                                                          \
  {                                                                          \
    f4v s_[4];                                                               \
    _Pragma("unroll") for (int ns = 0; ns < 4; ++ns) {                       \
      f4v u_ = (f4v)0.0f;                                                    \
      u_ = __builtin_amdgcn_mfma_f32_16x16x32_bf16(kf[ns][0], aq[t][0], u_, 0, 0, 0); \
      u_ = __builtin_amdgcn_mfma_f32_16x16x32_bf16(kf[ns][1], aq[t][1], u_, 0, 0, 0); \
      s_[ns] = u_;                                                           \
    }                                                                        \
    const int qr_ = (qb) + m;                                                \
    union { unsigned u[4]; s8v v; } paA_, paB_;                              \
    _Pragma("unroll") for (int ns = 0; ns < 4; ++ns) {                       \
      const int sb_ = s0 + ns * 16 + quad * 4;                               \
      const float p0 = (sb_     > qr_) ? 0.f : __builtin_amdgcn_exp2f(s_[ns][0]); \
      const float p1 = (sb_ + 1 > qr_) ? 0.f : __builtin_amdgcn_exp2f(s_[ns][1]); \
      const float p2 = (sb_ + 2 > qr_) ? 0.f : __builtin_amdgcn_exp2f(s_[ns][2]); \
      const float p3 = (sb_ + 3 > qr_) ? 0.f : __builtin_amdgcn_exp2f(s_[ns][3]); \
      li[t] += (p0 + p1) + (p2 + p3);                                        \
      if (ns < 2) {                                                          \
        paA_.u[ns * 2] = pk2(p0, p1); paA_.u[ns * 2 + 1] = pk2(p2, p3);      \
      } else {                                                               \
        paB_.u[(ns - 2) * 2] = pk2(p0, p1);                                  \
        paB_.u[(ns - 2) * 2 + 1] = pk2(p2, p3);                              \
      }                                                                      \
    }                                                                        \
    _Pragma("unroll") for (int hn = 0; hn < 4; ++hn) {                       \
      o[t][hn] = __builtin_amdgcn_mfma_f32_16x16x32_bf16(paA_.v, vf[hn][0], o[t][hn], 0, 0, 0); \
      o[t][hn] = __builtin_amdgcn_mfma_f32_16x16x32_bf16(paB_.v, vf[hn][1], o[t][hn], 0, 0, 0); \
    }                                                                        \
  }

  for (int st = wv; st < nstB; st += 8) {
    const int s0 = st * 64;

    s8v kf[4][2];
#pragma unroll
    for (int ns = 0; ns < 4; ++ns) {
      const unsigned short* kp = &kbase[(size_t)(s0 + ns * 16 + m) * HS + quad * 8];
      kf[ns][0] = *(const s8v*)kp;
      kf[ns][1] = *(const s8v*)(kp + 32);
    }
    s8v vf[4][2];
#pragma unroll
    for (int hn = 0; hn < 4; ++hn) {
      const unsigned short* vp = &vbase[(size_t)(hn * 16 + m) * T_SEQ + s0 + quad * 8];
      vf[hn][0] = *(const s8v*)vp;
      vf[hn][1] = *(const s8v*)(vp + 32);
    }

    const bool low = (st < nstS);   // wave-uniform branch
    if (low) { TILE(0, qb0); TILE(1, qb1); }
    TILE(2, qb2);
    TILE(3, qb3);
  }
#undef TILE

  // li: lanes (m, quad=0..3) hold partials for q = qb+m -> reduce over quads
#pragma unroll
  for (int t = 0; t < 4; ++t) {
    float s = li[t];
    s += __shfl_xor(s, 16); s += __shfl_xor(s, 32);
    li[t] = s;
  }

  // merge: tiles 0,1 -> rows rS..; tiles 2,3 -> rows rB..
  const int row = tid >> 4, c4 = (tid & 15) * 4;
#pragma unroll
  for (int ps = 0; ps < 2; ++ps) {
    __syncthreads();   // previous pass reads complete
#pragma unroll
    for (int hn = 0; hn < 4; ++hn)
#pragma unroll
      for (int r = 0; r < 4; ++r) {
        mo[wv][quad * 4 + r][hn * 16 + m]      = o[2 * ps][hn][r];
        mo[wv][16 + quad * 4 + r][hn * 16 + m] = o[2 * ps + 1][hn][r];
      }
    if (quad == 0) {
      ml[wv][m]      = li[2 * ps];
      ml[wv][16 + m] = li[2 * ps + 1];
    }
    __syncthreads();

    float ls = 0.f;
#pragma unroll
    for (int w = 0; w < 8; ++w) ls += ml[w][row];
    const float inv = 1.0f / ls;
    float ax = 0.f, ay = 0.f, az = 0.f, aw = 0.f;
#pragma unroll
    for (int w = 0; w < 8; ++w) {
      float4 v = *(const float4*)&mo[w][row][c4];
      ax += v.x; ay += v.y; az += v.z; aw += v.w;
    }
    const int gr = ps ? grB : grS;
    float4 res;
    res.x = ax * inv; res.y = ay * inv; res.z = az * inv; res.w = aw * inv;
    *(float4*)&out[(size_t)(gr + row) * HS + c4] = res;
  }
}

extern "C" void kernel_launch(void* const* d_in, const int* in_sizes, int n_in,
                              void* d_out, int out_size, void* d_ws, size_t ws_size,
                              hipStream_t stream) {
  const float* x  = (const float*)d_in[0];
  const float* Wq = (const float*)d_in[1];
  const float* Wk = (const float*)d_in[2];
  const float* Wv = (const float*)d_in[3];
  float* out = (float*)d_out;

  unsigned short* qws  = (unsigned short*)d_ws;          // 2 MB
  unsigned short* kws  = qws + (size_t)BT * HS;          // 2 MB
  unsigned short* vtws = kws + (size_t)BT * HS;          // 2 MB
  unsigned short* wt   = vtws + (size_t)BT * HS;         // 384 KB

  wt_kernel<<<dim3(48), dim3(256), 0, stream>>>(Wq, Wk, Wv, wt);
  qkv_kernel<<<dim3(BT / 64), dim3(512), 0, stream>>>(x, wt, qws, kws, vtws);
  attn_kernel<<<dim3(256), dim3(512), 0, stream>>>(qws, kws, vtws, out);
}